// Round 8
// baseline (178.472 us; speedup 1.0000x reference)
//
#include <hip/hip_runtime.h>
#include <hip/hip_bf16.h>
#include <stdint.h>

typedef __attribute__((ext_vector_type(4))) float f32x4;
typedef __attribute__((ext_vector_type(8))) short short8;
typedef __attribute__((ext_vector_type(4))) int int4v;

#define IN_F   8192
#define OUT_F  8192
#define MROWS  256
#define NGRP   128   // IN_F / 64
#define QROW   4096  // int32s per q_weight row (each int32 holds ONE packed byte)
#define NSLICE 8     // split-K slices
#define KT_PER 16    // k-tiles (BK=64) per slice

// Static device scratch — no dependence on d_ws/ws_size.
__device__ unsigned short g_xb[MROWS * IN_F];             // 4 MB bf16 x, fragment-major
__device__ float          g_t[MROWS * 16];                // LoRA intermediate
__device__ float          g_part[NSLICE * MROWS * OUT_F]; // 64 MB split-K partials

// NF4 levels: Phi^{-1}((i+0.5)/16) / Phi^{-1}(15.5/16)
__device__ __constant__ float NF4_LVL[16] = {
  -1.0f,        -0.70756721f, -0.54221982f, -0.41681853f,
  -0.31090474f, -0.21594601f, -0.12734085f, -0.04209530f,
   0.04209530f,  0.12734085f,  0.21594601f,  0.31090474f,
   0.41681853f,  0.54221982f,  0.70756721f,  1.0f };

static __device__ inline uint32_t pkbf(float a, float b) {
  __bf16 ha = (__bf16)a, hb = (__bf16)b;
  return (uint32_t)__builtin_bit_cast(unsigned short, ha)
       | ((uint32_t)__builtin_bit_cast(unsigned short, hb) << 16);
}

// ---- k0: x fp32 -> bf16, fragment-major:
// 16B-chunk d: l15=d&15, sub=(d>>4)&3, kk=(d>>6)&1, m16=(d>>7)&15, kt=d>>11
// holds x[m16*16+l15][kt*64 + (kk*4+sub)*8 .. +8].
__global__ __launch_bounds__(256) void k_convert(const float* __restrict__ x) {
  int d = blockIdx.x * 256 + threadIdx.x;   // 262144 chunks
  int l15 = d & 15, sub = (d >> 4) & 3, kk = (d >> 6) & 1;
  int m16 = (d >> 7) & 15, kt = d >> 11;
  int r = m16 * 16 + l15;
  int k = kt * 64 + (kk * 4 + sub) * 8;
  const float* src = x + (size_t)r * IN_F + k;
  f32x4 v0 = *(const f32x4*)src;
  f32x4 v1 = *(const f32x4*)(src + 4);
  int4v ov;
  ov[0] = (int)pkbf(v0.x, v0.y); ov[1] = (int)pkbf(v0.z, v0.w);
  ov[2] = (int)pkbf(v1.x, v1.y); ov[3] = (int)pkbf(v1.z, v1.w);
  *(int4v*)(g_xb + (size_t)d * 8) = ov;
}

// ---- k1: g_t = 2 * x @ lora_A^T
__global__ __launch_bounds__(256) void k_xa(const float* __restrict__ x,
                                            const float* __restrict__ lora_A) {
  int m = blockIdx.x, tid = threadIdx.x;
  float acc[16];
#pragma unroll
  for (int r = 0; r < 16; ++r) acc[r] = 0.f;
  const float* xr = x + (size_t)m * IN_F;
  for (int it = 0; it < 8; ++it) {
    int k = (tid + it * 256) * 4;
    f32x4 xv = *(const f32x4*)(xr + k);
#pragma unroll
    for (int r = 0; r < 16; ++r) {
      f32x4 av = *(const f32x4*)(lora_A + (size_t)r * IN_F + k);
      acc[r] += xv.x * av.x + xv.y * av.y + xv.z * av.z + xv.w * av.w;
    }
  }
#pragma unroll
  for (int r = 0; r < 16; ++r) {
    float v = acc[r];
#pragma unroll
    for (int off = 32; off; off >>= 1) v += __shfl_xor(v, off, 64);
    acc[r] = v;
  }
  __shared__ float sm[4][16];
  int lane = tid & 63, wave = tid >> 6;
  if (lane == 0) {
#pragma unroll
    for (int r = 0; r < 16; ++r) sm[wave][r] = acc[r];
  }
  __syncthreads();
  if (tid < 16)
    g_t[m * 16 + tid] = 2.0f * (sm[0][tid] + sm[1][tid] + sm[2][tid] + sm[3][tid]);
}

// ---- k3: main GEMM, max-TLP streaming. 2048 independent blocks (BN=32, split-K=8),
// 256 thr = 4 waves, no intra-loop barriers. Per wave: M64 x N32.
// B: q int32s -> regs (prefetched 1 tile ahead) -> packed-LUT dequant -> MFMA B-frags.
// A: fragment-major g_xb, disjoint rows per wave (no duplicate L2 traffic).
__global__ __launch_bounds__(256, 4) void k_gemm(
    const int* __restrict__ qw, const float* __restrict__ scales)
{
  __shared__ uint32_t lut2[256];   // packed bf16 pair: low short = lv[hi-nibble]
  int tid = threadIdx.x;
  int lane = tid & 63, wave = tid >> 6;
  lut2[tid] = pkbf(NF4_LVL[tid >> 4], NF4_LVL[tid & 15]);
  __syncthreads();   // the only barrier in the kernel

  // XCD swizzle over 2048 blocks: XCD x gets wg in [x*256, x*256+256) -> one bz per XCD
  int flat = blockIdx.x;
  int wg = (flat & 7) * 256 + (flat >> 3);
  int bx = wg & 255, bz = wg >> 8;     // bx: n-tile (32 cols), bz: k-slice
  int n0 = bx * 32;
  int ktg0 = bz * KT_PER;

  int wr = wave;                // M group: rows wr*64 .. wr*64+63
  int sub = lane >> 4, l15 = lane & 15;

  // B-side: per lane 2 q-rows (ni*16 apart)
  size_t row0 = (size_t)(n0 + l15);
  const int* qb0 = qw + row0 * QROW + sub * 4;
  const int* qb1 = qb0 + 16 * QROW;
  const float* sb0 = scales + row0 * NGRP;
  const float* sb1 = sb0 + 16 * NGRP;

  // A-side: frag(kt, m16, kk) at (kt*16+m16)*1024 + kk*512 ushorts
  const unsigned short* abase =
      g_xb + (size_t)ktg0 * 16384 + (wr * 4) * 1024 + (sub * 16 + l15) * 8;

  f32x4 acc[4][2];
#pragma unroll
  for (int i = 0; i < 4; ++i)
#pragma unroll
    for (int j = 0; j < 2; ++j) acc[i][j] = (f32x4){0.f, 0.f, 0.f, 0.f};

  // prefetch q/scales for tile 0
  int4v qb[4];    // [ni*2+kk]
  float sb[2];
  {
    size_t ko = (size_t)ktg0 * 32;
    qb[0] = *(const int4v*)(qb0 + ko);
    qb[1] = *(const int4v*)(qb0 + ko + 16);
    qb[2] = *(const int4v*)(qb1 + ko);
    qb[3] = *(const int4v*)(qb1 + ko + 16);
    sb[0] = sb0[ktg0]; sb[1] = sb1[ktg0];
  }

#pragma clang loop unroll(disable)
  for (int t = 0; t < KT_PER; ++t) {
    // A fragments for this tile (8 x 16B per lane, from L2)
    short8 af[2][4];
    const unsigned short* ab = abase + (size_t)t * 16384;
#pragma unroll
    for (int kk = 0; kk < 2; ++kk)
#pragma unroll
      for (int mi = 0; mi < 4; ++mi)
        af[kk][mi] = *(const short8*)(ab + mi * 1024 + kk * 512);

    // prefetch q/scales for tile t+1 (in flight under this tile's work)
    int tn = (t < KT_PER - 1) ? (t + 1) : t;
    size_t ko = (size_t)(ktg0 + tn) * 32;
    int4v qn[4];
    float sn[2];
    qn[0] = *(const int4v*)(qb0 + ko);
    qn[1] = *(const int4v*)(qb0 + ko + 16);
    qn[2] = *(const int4v*)(qb1 + ko);
    qn[3] = *(const int4v*)(qb1 + ko + 16);
    sn[0] = sb0[ktg0 + tn]; sn[1] = sb1[ktg0 + tn];

    // dequant current q -> B frags (each int32 holds ONE byte = 2 nibbles)
    short8 bq[4];   // [ni*2+kk]
#pragma unroll
    for (int u = 0; u < 4; ++u) {
      float s = sb[u >> 1];
      int4v q = qb[u];
      int4v ov;
#pragma unroll
      for (int e = 0; e < 4; ++e) {
        uint32_t pk = lut2[q[e] & 255];
        float fh = __builtin_bit_cast(float, pk << 16);
        float fl = __builtin_bit_cast(float, pk & 0xFFFF0000u);
        ov[e] = (int)pkbf(fh * s, fl * s);
      }
      bq[u] = __builtin_bit_cast(short8, ov);
    }
#pragma unroll
    for (int i = 0; i < 4; ++i) qb[i] = qn[i];
    sb[0] = sn[0]; sb[1] = sn[1];

#pragma unroll
    for (int kk = 0; kk < 2; ++kk)
#pragma unroll
      for (int mi = 0; mi < 4; ++mi)
#pragma unroll
        for (int ni = 0; ni < 2; ++ni)
          acc[mi][ni] = __builtin_amdgcn_mfma_f32_16x16x32_bf16(
              af[kk][mi], bq[ni * 2 + kk], acc[mi][ni], 0, 0, 0);
  }

  // epilogue -> per-slice partials. D layout: col=lane&15, row=(lane>>4)*4+reg
  float* op = g_part + (size_t)bz * MROWS * OUT_F;
#pragma unroll
  for (int mi = 0; mi < 4; ++mi) {
#pragma unroll
    for (int ni = 0; ni < 2; ++ni) {
      int m = wr * 64 + mi * 16 + sub * 4;
      int nn = n0 + ni * 16 + l15;
#pragma unroll
      for (int j = 0; j < 4; ++j)
        op[(size_t)(m + j) * OUT_F + nn] = acc[mi][ni][j];
    }
  }
}

// ---- k4: out = sum of 8 split-K partials + LoRA (g_t @ lora_B^T), fused
__global__ __launch_bounds__(256) void k_reduce(const float* __restrict__ lora_B,
                                                float* __restrict__ out) {
  size_t i = ((size_t)blockIdx.x * 256 + threadIdx.x) * 4;
  int m = (int)(i >> 13);
  int n = (int)(i & 8191);
  f32x4 v = *(const f32x4*)(g_part + i);
#pragma unroll
  for (int s = 1; s < NSLICE; ++s)
    v += *(const f32x4*)(g_part + (size_t)s * MROWS * OUT_F + i);
  const float* tr = g_t + m * 16;
  f32x4 t0 = *(const f32x4*)tr,       t1 = *(const f32x4*)(tr + 4);
  f32x4 t2 = *(const f32x4*)(tr + 8), t3 = *(const f32x4*)(tr + 12);
#pragma unroll
  for (int j = 0; j < 4; ++j) {
    const float* br = lora_B + (size_t)(n + j) * 16;
    f32x4 b0 = *(const f32x4*)br,       b1 = *(const f32x4*)(br + 4);
    f32x4 b2 = *(const f32x4*)(br + 8), b3 = *(const f32x4*)(br + 12);
    v[j] += t0.x*b0.x + t0.y*b0.y + t0.z*b0.z + t0.w*b0.w
          + t1.x*b1.x + t1.y*b1.y + t1.z*b1.z + t1.w*b1.w
          + t2.x*b2.x + t2.y*b2.y + t2.z*b2.z + t2.w*b2.w
          + t3.x*b3.x + t3.y*b3.y + t3.z*b3.z + t3.w*b3.w;
  }
  *(f32x4*)(out + i) = v;
}

extern "C" void kernel_launch(void* const* d_in, const int* in_sizes, int n_in,
                              void* d_out, int out_size, void* d_ws, size_t ws_size,
                              hipStream_t stream) {
  const float* x  = (const float*)d_in[0];
  const int*   qw = (const int*)d_in[1];
  const float* sc = (const float*)d_in[2];
  const float* lA = (const float*)d_in[3];
  const float* lB = (const float*)d_in[4];
  float* out = (float*)d_out;

  k_convert<<<1024, 256, 0, stream>>>(x);
  k_xa<<<256, 256, 0, stream>>>(x, lA);
  k_gemm<<<2048, 256, 0, stream>>>(qw, sc);
  k_reduce<<<2048, 256, 0, stream>>>(lB, out);
}

// Round 10
// 129.176 us; speedup vs baseline: 1.3816x; 1.3816x over previous
//
#include <hip/hip_runtime.h>
#include <hip/hip_bf16.h>
#include <stdint.h>

typedef __attribute__((ext_vector_type(4))) float f32x4;
typedef __attribute__((ext_vector_type(8))) short short8;
typedef __attribute__((ext_vector_type(4))) int int4v;

#define IN_F   8192
#define OUT_F  8192
#define MROWS  256
#define NGRP   128   // IN_F / 64
#define QROW   4096  // int32s per q_weight row (each int32 holds ONE packed byte)
#define NSLICE 4     // split-K slices
#define KT_PER 32    // k-tiles (BK=64) per slice: 4*32*64 = 8192 = full K

// Static device scratch — no dependence on d_ws/ws_size.
__device__ unsigned short g_xb[MROWS * IN_F];             // 4 MB bf16 x, fragment-major
__device__ float          g_t[MROWS * 16];                // LoRA intermediate
__device__ float          g_part[NSLICE * MROWS * OUT_F]; // 32 MB split-K partials

// NF4 levels: Phi^{-1}((i+0.5)/16) / Phi^{-1}(15.5/16)
__device__ __constant__ float NF4_LVL[16] = {
  -1.0f,        -0.70756721f, -0.54221982f, -0.41681853f,
  -0.31090474f, -0.21594601f, -0.12734085f, -0.04209530f,
   0.04209530f,  0.12734085f,  0.21594601f,  0.31090474f,
   0.41681853f,  0.54221982f,  0.70756721f,  1.0f };

static __device__ inline uint32_t pkbf(float a, float b) {
  __bf16 ha = (__bf16)a, hb = (__bf16)b;
  return (uint32_t)__builtin_bit_cast(unsigned short, ha)
       | ((uint32_t)__builtin_bit_cast(unsigned short, hb) << 16);
}

// ---- k0: x fp32 -> bf16, fragment-major:
// 16B-chunk d: l15=d&15, sub=(d>>4)&3, kk=(d>>6)&1, m16=(d>>7)&15, kt=d>>11
// holds x[m16*16+l15][kt*64 + (kk*4+sub)*8 .. +8].
__global__ __launch_bounds__(256) void k_convert(const float* __restrict__ x) {
  int d = blockIdx.x * 256 + threadIdx.x;   // 262144 chunks
  int l15 = d & 15, sub = (d >> 4) & 3, kk = (d >> 6) & 1;
  int m16 = (d >> 7) & 15, kt = d >> 11;
  int r = m16 * 16 + l15;
  int k = kt * 64 + (kk * 4 + sub) * 8;
  const float* src = x + (size_t)r * IN_F + k;
  f32x4 v0 = *(const f32x4*)src;
  f32x4 v1 = *(const f32x4*)(src + 4);
  int4v ov;
  ov[0] = (int)pkbf(v0.x, v0.y); ov[1] = (int)pkbf(v0.z, v0.w);
  ov[2] = (int)pkbf(v1.x, v1.y); ov[3] = (int)pkbf(v1.z, v1.w);
  *(int4v*)(g_xb + (size_t)d * 8) = ov;
}

// ---- k1: g_t = 2 * x @ lora_A^T
__global__ __launch_bounds__(256) void k_xa(const float* __restrict__ x,
                                            const float* __restrict__ lora_A) {
  int m = blockIdx.x, tid = threadIdx.x;
  float acc[16];
#pragma unroll
  for (int r = 0; r < 16; ++r) acc[r] = 0.f;
  const float* xr = x + (size_t)m * IN_F;
  for (int it = 0; it < 8; ++it) {
    int k = (tid + it * 256) * 4;
    f32x4 xv = *(const f32x4*)(xr + k);
#pragma unroll
    for (int r = 0; r < 16; ++r) {
      f32x4 av = *(const f32x4*)(lora_A + (size_t)r * IN_F + k);
      acc[r] += xv.x * av.x + xv.y * av.y + xv.z * av.z + xv.w * av.w;
    }
  }
#pragma unroll
  for (int r = 0; r < 16; ++r) {
    float v = acc[r];
#pragma unroll
    for (int off = 32; off; off >>= 1) v += __shfl_xor(v, off, 64);
    acc[r] = v;
  }
  __shared__ float sm[4][16];
  int lane = tid & 63, wave = tid >> 6;
  if (lane == 0) {
#pragma unroll
    for (int r = 0; r < 16; ++r) sm[wave][r] = acc[r];
  }
  __syncthreads();
  if (tid < 16)
    g_t[m * 16 + tid] = 2.0f * (sm[0][tid] + sm[1][tid] + sm[2][tid] + sm[3][tid]);
}

// ---- k3: main GEMM. 1024 blocks (2 m-tiles x 128 n-tiles x split-K=4),
// 256 thr = 4 waves (2m x 2n), per-wave 64x32, BK=64, ~4 blocks/CU.
// B: q -> regs (1 tile ahead) -> UNSCALED LUT bytes -> LDS dbuf; scale folded post-MFMA
// in fp32 (per-lane s matches D-frag col). A: direct L2 loads from fragment-major g_xb.
// One raw barrier per tile, lgkmcnt(0) only — q prefetch stays in flight.
__global__ __launch_bounds__(256, 4) void k_gemm(
    const int* __restrict__ qw, const float* __restrict__ scales)
{
  __shared__ unsigned short Bl[2][64 * 64];  // 2 x 8 KB (unscaled bf16 levels)
  __shared__ uint32_t lut2[256];             // packed bf16 pair (lv[hi], lv[lo])

  int tid = threadIdx.x;
  int lane = tid & 63, wave = tid >> 6;
  lut2[tid] = pkbf(NF4_LVL[tid >> 4], NF4_LVL[tid & 15]);

  // XCD-aware bijective swizzle over 1024 blocks
  int flat = blockIdx.x;
  int wg = (flat & 7) * 128 + (flat >> 3);
  int bx = wg & 127;            // n-tile (64 cols)
  int mt = (wg >> 7) & 1;       // m-tile (128 rows)
  int bz = wg >> 8;             // k-slice
  int n0 = bx * 64;
  int m0 = mt * 128;
  int ktg0 = bz * KT_PER;

  int wr = wave >> 1, wc = wave & 1;
  int sub = lane >> 4, l15 = lane & 15;

  // staging geometry: 2 units/thread; unit u -> (row, chunk c); chunk = 8 weights (4 ints)
  int r0 = tid >> 3, c0 = tid & 7;          // unit 0: rows 0..31
  int r1 = (tid + 256) >> 3, c1 = c0;       // unit 1: rows 32..63
  const int* qp0 = qw + (size_t)(n0 + r0) * QROW + c0 * 4;
  const int* qp1 = qw + (size_t)(n0 + r1) * QROW + c1 * 4;
  int boff0 = r0 * 128 + ((c0 ^ (r0 & 7)) << 4);
  int boff1 = r1 * 128 + ((c1 ^ (r1 & 7)) << 4);

  // per-lane scale rows (= output cols of this wave's frags)
  const float* sp0 = scales + (size_t)(n0 + wc * 32 + l15) * NGRP;
  const float* sp1 = sp0 + 16 * NGRP;

  // A-side: frag(kt, m16, kk) at (kt*16+m16)*1024 + (sub*16+l15)*8 ushorts
  const unsigned short* abase =
      g_xb + (size_t)(mt * 8 + wr * 4) * 1024 + (sub * 16 + l15) * 8;

  f32x4 acc[4][2];
#pragma unroll
  for (int i = 0; i < 4; ++i)
#pragma unroll
    for (int j = 0; j < 2; ++j) acc[i][j] = (f32x4){0.f, 0.f, 0.f, 0.f};

  auto dqst = [&](int buf, int4v q0, int4v q1) {
    int4v ov;
#pragma unroll
    for (int e = 0; e < 4; ++e) ov[e] = (int)lut2[q0[e] & 255];
    *(int4v*)((char*)(&Bl[buf][0]) + boff0) = ov;
#pragma unroll
    for (int e = 0; e < 4; ++e) ov[e] = (int)lut2[q1[e] & 255];
    *(int4v*)((char*)(&Bl[buf][0]) + boff1) = ov;
  };

  __syncthreads();  // lut ready

  // prologue: q(tile0) -> Bl[0]; q(tile1), s(tile0), s(tile1) in regs
  {
    size_t ko = (size_t)ktg0 * 32;
    int4v qa0 = *(const int4v*)(qp0 + ko);
    int4v qa1 = *(const int4v*)(qp1 + ko);
    dqst(0, qa0, qa1);
  }
  int4v qn0 = *(const int4v*)(qp0 + (size_t)(ktg0 + 1) * 32);
  int4v qn1 = *(const int4v*)(qp1 + (size_t)(ktg0 + 1) * 32);
  float sc0 = sp0[ktg0],     sc1 = sp1[ktg0];
  float sx0 = sp0[ktg0 + 1], sx1 = sp1[ktg0 + 1];
  asm volatile("s_waitcnt lgkmcnt(0)" ::: "memory");
  __builtin_amdgcn_s_barrier();

  for (int t = 0; t < KT_PER; ++t) {
    int cur = t & 1;
    int ktg = ktg0 + t;

    // A frags for this tile (8 x dwordx4 from L2)
    short8 af[2][4];
    const unsigned short* ab = abase + (size_t)ktg * 16384;
#pragma unroll
    for (int kk = 0; kk < 2; ++kk)
#pragma unroll
      for (int mi = 0; mi < 4; ++mi)
        af[kk][mi] = *(const short8*)(ab + mi * 1024 + kk * 512);

    // prefetch q/s for tile t+2 (stay in flight across the barrier)
    int4v qf0, qf1;
    float sf0 = 0.f, sf1 = 0.f;
    if (t < KT_PER - 2) {
      size_t ko = (size_t)(ktg + 2) * 32;
      qf0 = *(const int4v*)(qp0 + ko);
      qf1 = *(const int4v*)(qp1 + ko);
      sf0 = sp0[ktg + 2]; sf1 = sp1[ktg + 2];
    }

    // stage tile t+1 (unscaled) into Bl[cur^1]
    if (t < KT_PER - 1) dqst(cur ^ 1, qn0, qn1);

    // compute tile t: tacc per ni, then fold scale in fp32
#pragma unroll
    for (int ni = 0; ni < 2; ++ni) {
      short8 bfv[2];
#pragma unroll
      for (int kk = 0; kk < 2; ++kk) {
        int n = wc * 32 + ni * 16 + l15;
        int cch = (kk * 4 + sub) ^ (n & 7);
        bfv[kk] = *(const short8*)((const char*)(&Bl[cur][0]) + n * 128 + cch * 16);
      }
      f32x4 tacc[4];
#pragma unroll
      for (int mi = 0; mi < 4; ++mi) tacc[mi] = (f32x4){0.f, 0.f, 0.f, 0.f};
      __builtin_amdgcn_s_setprio(1);
#pragma unroll
      for (int kk = 0; kk < 2; ++kk)
#pragma unroll
        for (int mi = 0; mi < 4; ++mi)
          tacc[mi] = __builtin_amdgcn_mfma_f32_16x16x32_bf16(
              af[kk][mi], bfv[kk], tacc[mi], 0, 0, 0);
      __builtin_amdgcn_s_setprio(0);
      float s = ni ? sc1 : sc0;
#pragma unroll
      for (int mi = 0; mi < 4; ++mi) {
        acc[mi][ni].x += s * tacc[mi].x;
        acc[mi][ni].y += s * tacc[mi].y;
        acc[mi][ni].z += s * tacc[mi].z;
        acc[mi][ni].w += s * tacc[mi].w;
      }
    }

    qn0 = qf0; qn1 = qf1;
    sc0 = sx0; sc1 = sx1;
    sx0 = sf0; sx1 = sf1;

    if (t < KT_PER - 1) {
      asm volatile("s_waitcnt lgkmcnt(0)" ::: "memory");
      __builtin_amdgcn_s_barrier();
    }
  }

  // epilogue -> per-slice partials. D layout: col=lane&15, row=(lane>>4)*4+reg
  float* op = g_part + (size_t)bz * MROWS * OUT_F;
#pragma unroll
  for (int mi = 0; mi < 4; ++mi) {
#pragma unroll
    for (int ni = 0; ni < 2; ++ni) {
      int m = m0 + wr * 64 + mi * 16 + sub * 4;
      int nn = n0 + wc * 32 + ni * 16 + l15;
#pragma unroll
      for (int j = 0; j < 4; ++j)
        op[(size_t)(m + j) * OUT_F + nn] = acc[mi][ni][j];
    }
  }
}

// ---- k4: out = sum of 4 split-K partials + LoRA (g_t @ lora_B^T), fused
__global__ __launch_bounds__(256) void k_reduce(const float* __restrict__ lora_B,
                                                float* __restrict__ out) {
  size_t i = ((size_t)blockIdx.x * 256 + threadIdx.x) * 4;
  int m = (int)(i >> 13);
  int n = (int)(i & 8191);
  f32x4 v = *(const f32x4*)(g_part + i);
#pragma unroll
  for (int s = 1; s < NSLICE; ++s)
    v += *(const f32x4*)(g_part + (size_t)s * MROWS * OUT_F + i);
  const float* tr = g_t + m * 16;
  f32x4 t0 = *(const f32x4*)tr,       t1 = *(const f32x4*)(tr + 4);
  f32x4 t2 = *(const f32x4*)(tr + 8), t3 = *(const f32x4*)(tr + 12);
#pragma unroll
  for (int j = 0; j < 4; ++j) {
    const float* br = lora_B + (size_t)(n + j) * 16;
    f32x4 b0 = *(const f32x4*)br,       b1 = *(const f32x4*)(br + 4);
    f32x4 b2 = *(const f32x4*)(br + 8), b3 = *(const f32x4*)(br + 12);
    v[j] += t0.x*b0.x + t0.y*b0.y + t0.z*b0.z + t0.w*b0.w
          + t1.x*b1.x + t1.y*b1.y + t1.z*b1.z + t1.w*b1.w
          + t2.x*b2.x + t2.y*b2.y + t2.z*b2.z + t2.w*b2.w
          + t3.x*b3.x + t3.y*b3.y + t3.z*b3.z + t3.w*b3.w;
  }
  *(f32x4*)(out + i) = v;
}

extern "C" void kernel_launch(void* const* d_in, const int* in_sizes, int n_in,
                              void* d_out, int out_size, void* d_ws, size_t ws_size,
                              hipStream_t stream) {
  const float* x  = (const float*)d_in[0];
  const int*   qw = (const int*)d_in[1];
  const float* sc = (const float*)d_in[2];
  const float* lA = (const float*)d_in[3];
  const float* lB = (const float*)d_in[4];
  float* out = (float*)d_out;

  k_convert<<<1024, 256, 0, stream>>>(x);
  k_xa<<<256, 256, 0, stream>>>(x, lA);
  k_gemm<<<1024, 256, 0, stream>>>(qw, sc);
  k_reduce<<<2048, 256, 0, stream>>>(lB, out);
}